// Round 2
// baseline (407.966 us; speedup 1.0000x reference)
//
#include <hip/hip_runtime.h>

typedef _Float16 half8 __attribute__((ext_vector_type(8)));
typedef __attribute__((ext_vector_type(4))) float f32x4;

__device__ __forceinline__ unsigned short f2h(float f) {
    _Float16 h = (_Float16)f;
    return *(unsigned short*)&h;
}
__device__ __forceinline__ float h2f(unsigned short u) {
    _Float16 h = *(_Float16*)&u;
    return (float)h;
}

// ---------- x -> f16 table ----------

__global__ __launch_bounds__(256) void xprep_kernel(
    const float* __restrict__ x, unsigned short* __restrict__ xh, int total8)
{
    int i = blockIdx.x * 256 + threadIdx.x;   // one thread = 8 elements
    if (i >= total8) return;
    const f32x4* p = (const f32x4*)(x + (size_t)i * 8);
    f32x4 u = p[0], v = p[1];
    half8 o;
#pragma unroll
    for (int j = 0; j < 4; ++j) {
        o[j] = (_Float16)u[j];
        o[j + 4] = (_Float16)v[j];
    }
    *(half8*)(xh + (size_t)i * 8) = o;
}

// ---------- preprocessing: counting sort by key = dst*8 + rel ----------

__global__ __launch_bounds__(256) void hist8_kernel(
    const int* __restrict__ dst, const int* __restrict__ et,
    int* __restrict__ hist, int* __restrict__ rank, int E)
{
    int e = blockIdx.x * 256 + threadIdx.x;
    if (e < E) rank[e] = atomicAdd(&hist[dst[e] * 8 + et[e]], 1);
}

#define SCAN_TILE 4096
__global__ __launch_bounds__(1024) void scanA_kernel(
    const int* __restrict__ hist, int* __restrict__ bstart,
    int* __restrict__ partial, int nkeys)
{
    __shared__ int wsum[16];
    const int t = threadIdx.x;
    const int lane = t & 63, w = t >> 6;
    const int base = blockIdx.x * SCAN_TILE + t * 4;
    int v[4];
    int s = 0;
#pragma unroll
    for (int i = 0; i < 4; ++i) {
        v[i] = (base + i < nkeys) ? hist[base + i] : 0;
        s += v[i];
    }
    int inc = s;
#pragma unroll
    for (int off = 1; off < 64; off <<= 1) {
        int u = __shfl_up(inc, off);
        if (lane >= off) inc += u;
    }
    if (lane == 63) wsum[w] = inc;
    __syncthreads();
    if (w == 0 && lane < 16) {
        int ws = wsum[lane];
        int winc = ws;
#pragma unroll
        for (int off = 1; off < 16; off <<= 1) {
            int u = __shfl_up(winc, off);
            if (lane >= off) winc += u;
        }
        wsum[lane] = winc - ws;   // exclusive
    }
    __syncthreads();
    int run = wsum[w] + (inc - s);
    int tbase = run;
#pragma unroll
    for (int i = 0; i < 4; ++i) {
        if (base + i < nkeys) bstart[base + i] = run;
        run += v[i];
    }
    if (t == 1023) partial[blockIdx.x] = tbase + s;   // block total
}

__global__ __launch_bounds__(64) void scanB_kernel(
    const int* __restrict__ partial, int* __restrict__ pscan,
    int* __restrict__ bstart_end, int nblk)
{
    const int lane = threadIdx.x;
    int running = 0;
    for (int b = 0; b < nblk; b += 64) {
        int i = b + lane;
        int o = (i < nblk) ? partial[i] : 0;
        int v = o;
#pragma unroll
        for (int off = 1; off < 64; off <<= 1) {
            int u = __shfl_up(v, off);
            if (lane >= off) v += u;
        }
        if (i < nblk) pscan[i] = running + v - o;
        running += __shfl(v, 63);
    }
    if (lane == 0) *bstart_end = running;   // == E
}

__global__ __launch_bounds__(1024) void scanC_kernel(
    int* __restrict__ bstart, const int* __restrict__ pscan, int nkeys)
{
    int i = blockIdx.x * 1024 + threadIdx.x;
    if (i < nkeys) bstart[i] += pscan[i / SCAN_TILE];
}

// scatter: record = src only (rel/scale recovered from segment structure)
__global__ __launch_bounds__(256) void scatter_kernel(
    const int* __restrict__ src, const int* __restrict__ dst,
    const int* __restrict__ et, const int* __restrict__ rank,
    const int* __restrict__ bstart, unsigned* __restrict__ srt, int E)
{
    int e = blockIdx.x * 256 + threadIdx.x;
    if (e < E) {
        int key = dst[e] * 8 + et[e];
        srt[bstart[key] + rank[e]] = (unsigned)src[e];
    }
}

// ---------- W preconversion: chunk c in {root, W_0..7}: [c][j][k stride 72] ----------

__global__ __launch_bounds__(256) void wprep_kernel(
    const float* __restrict__ W, const float* __restrict__ root,
    unsigned short* __restrict__ wb, int dout)
{
    int idx = blockIdx.x * 256 + threadIdx.x;
    int total = 9 * 64 * dout;
    if (idx >= total) return;
    int c = idx / (64 * dout);
    int rme = idx % (64 * dout);
    int kk = rme / dout;
    int j = rme % dout;
    float f = (c == 0) ? root[kk * dout + j]
                       : W[(size_t)(c - 1) * 64 * dout + kk * dout + j];
    wb[(size_t)c * dout * 72 + (size_t)j * 72 + kk] = f2h(f);
}

// ---------- aggregation: per-(node,rel) means of a 64-wide f16 table ----------
// Edges sorted by (dst,rel); one wave per node, lane = feature.
// Single accumulator + wave-uniform boundary flush (edges rel-sorted within node).
// Gather table is 12.8 MB -> L2/L3 resident; M writes are 128B coalesced.

__global__ __launch_bounds__(512) void aggM_kernel(
    const unsigned short* __restrict__ tab,  // (N,64) f16 gather table
    const unsigned* __restrict__ srt,        // src per edge
    const int* __restrict__ bstart,          // (N*8 + 1)
    unsigned short* __restrict__ M,          // (N,512) f16 means
    int n_nodes)
{
    const int t = threadIdx.x;
    const int lane = t & 63;
    const int node = blockIdx.x * 8 + (t >> 6);
    if (node >= n_nodes) return;
    int myb = 0;
    if (lane < 9) myb = bstart[node * 8 + lane];
    const int e0 = __shfl(myb, 0);
    const int e1 = __shfl(myb, 8);
    unsigned short* mrow = M + (size_t)node * 512;

    int r = 0;
    int bprev = e0;
    int bnext = __shfl(myb, 1);
    float acc = 0.f;

    auto flush_to = [&](int eabs) {
        while (r < 8 && eabs == bnext) {
            int cnt = bnext - bprev;
            mrow[r * 64 + lane] = f2h(acc * (cnt ? (1.0f / (float)cnt) : 0.0f));
            acc = 0.f;
            bprev = bnext;
            ++r;
            bnext = (r < 8) ? __shfl(myb, r + 1) : (e1 + 1);
        }
    };

    for (int base = e0; base < e1; base += 64) {
        const int blen = min(64, e1 - base);
        unsigned rec = 0;
        if (lane < blen) rec = srt[base + lane];
        int k = 0;
        for (; k + 4 <= blen; k += 4) {
            unsigned q0 = __shfl(rec, k), q1 = __shfl(rec, k + 1);
            unsigned q2 = __shfl(rec, k + 2), q3 = __shfl(rec, k + 3);
            float v0 = h2f(tab[(size_t)q0 * 64 + lane]);
            float v1 = h2f(tab[(size_t)q1 * 64 + lane]);
            float v2 = h2f(tab[(size_t)q2 * 64 + lane]);
            float v3 = h2f(tab[(size_t)q3 * 64 + lane]);
            flush_to(base + k);     acc += v0;
            flush_to(base + k + 1); acc += v1;
            flush_to(base + k + 2); acc += v2;
            flush_to(base + k + 3); acc += v3;
        }
        for (; k < blen; ++k) {
            unsigned q = __shfl(rec, k);
            float v = h2f(tab[(size_t)q * 64 + lane]);
            flush_to(base + k);
            acc += v;
        }
    }
    flush_to(e1);   // flush all trailing (incl. empty) relations
}

// ---------- dense: out = [X | M] @ [root; W_0..7] + b, f16 MFMA ----------
// Block = 128 nodes, 512 threads = 8 waves; wave = one 16-row m-tile, all j.
// Verified compute/epilogue layout (carried from prior passing kernel).

template <int DOUT, int RELU, int OUTH>
__global__ __launch_bounds__(512, 2) void dense_kernel(
    const unsigned short* __restrict__ X,   // (N,64) f16  (chunk 0)
    const unsigned short* __restrict__ M,   // (N,512) f16 (chunks 1..8)
    const unsigned short* __restrict__ wb,  // (9, DOUT, 72) f16
    const float* __restrict__ bias,
    float* __restrict__ outf,               // fp32 out (OUTH=0)
    unsigned short* __restrict__ outh,      // f16 out, stride 64 (OUTH=1)
    int n_nodes)
{
    constexpr int WSHORTS = 9 * DOUT * 72;  // 41472 (83KB) or 20736 (41.5KB)
    __shared__ __align__(16) unsigned short wt_s[WSHORTS];

    const int t = threadIdx.x;
    const int w = t >> 6, lane = t & 63;
    const int quad = lane >> 4, l16 = lane & 15;
    const int node0 = blockIdx.x * 128;
    const int row = min(node0 + w * 16 + l16, n_nodes - 1);
    const unsigned short* xrow = X + (size_t)row * 64;
    const unsigned short* mrow = M + (size_t)row * 512;

    // prefetch entire A row (9 chunks x 2 frags = 72 VGPRs)
    half8 a[18];
    a[0] = *(const half8*)(xrow + quad * 8);
    a[1] = *(const half8*)(xrow + 32 + quad * 8);
#pragma unroll
    for (int c = 1; c < 9; ++c) {
        a[2 * c]     = *(const half8*)(mrow + (c - 1) * 64 + quad * 8);
        a[2 * c + 1] = *(const half8*)(mrow + (c - 1) * 64 + 32 + quad * 8);
    }
    // stage entire W image
    {
        uint4* d4 = (uint4*)wt_s;
        const uint4* s4 = (const uint4*)wb;
        for (int i = t; i < WSHORTS / 8; i += 512) d4[i] = s4[i];
    }
    __syncthreads();

    constexpr int JPW = DOUT / 16;
    f32x4 d[JPW];
#pragma unroll
    for (int i = 0; i < JPW; ++i) d[i] = {0.f, 0.f, 0.f, 0.f};

#pragma unroll
    for (int c = 0; c < 9; ++c) {
#pragma unroll
        for (int jj = 0; jj < JPW; ++jj) {
            const int j = jj * 16 + l16;
            half8 b0 = *(const half8*)&wt_s[c * DOUT * 72 + j * 72 + quad * 8];
            half8 b1 = *(const half8*)&wt_s[c * DOUT * 72 + j * 72 + 32 + quad * 8];
            d[jj] = __builtin_amdgcn_mfma_f32_16x16x32_f16(a[2 * c], b0, d[jj], 0, 0, 0);
            d[jj] = __builtin_amdgcn_mfma_f32_16x16x32_f16(a[2 * c + 1], b1, d[jj], 0, 0, 0);
        }
    }

    // epilogue: C/D layout col = lane&15 (j), row = quad*4 + reg (m)
#pragma unroll
    for (int jj = 0; jj < JPW; ++jj) {
        const int j = jj * 16 + l16;
        const float bj = bias[j];
#pragma unroll
        for (int r = 0; r < 4; ++r) {
            const int node = node0 + w * 16 + quad * 4 + r;
            if (node < n_nodes) {
                float v = d[jj][r] + bj;
                if (RELU) v = fmaxf(v, 0.0f);
                if (OUTH) outh[(size_t)node * 64 + j] = f2h(v);
                else      outf[(size_t)node * DOUT + j] = v;
            }
        }
    }
}

extern "C" void kernel_launch(void* const* d_in, const int* in_sizes, int n_in,
                              void* d_out, int out_size, void* d_ws, size_t ws_size,
                              hipStream_t stream) {
    const float* x     = (const float*)d_in[0];
    const float* W1    = (const float*)d_in[1];
    const float* root1 = (const float*)d_in[2];
    const float* b1    = (const float*)d_in[3];
    const float* W2    = (const float*)d_in[4];
    const float* root2 = (const float*)d_in[5];
    const float* b2    = (const float*)d_in[6];
    const int*   src   = (const int*)d_in[7];
    const int*   dst   = (const int*)d_in[8];
    const int*   et    = (const int*)d_in[9];

    const int N = in_sizes[0] / 64;
    const int E = in_sizes[7];
    const int KEYS = N * 8;

    char* p = (char*)d_ws;
    auto alloc = [&](size_t bytes) {
        char* r = p;
        p += (bytes + 15) & ~(size_t)15;
        return r;
    };
    unsigned* srt       = (unsigned*)alloc((size_t)E * 4);
    int* rank           = (int*)alloc((size_t)E * 4);
    int* hist           = (int*)alloc((size_t)KEYS * 4);
    int* bstart         = (int*)alloc((size_t)(KEYS + 1) * 4);
    int* partial        = (int*)alloc(256 * 4);
    int* pscan          = (int*)alloc(256 * 4);
    unsigned short* wb1 = (unsigned short*)alloc((size_t)9 * 64 * 72 * 2);
    unsigned short* wb2 = (unsigned short*)alloc((size_t)9 * 32 * 72 * 2);
    unsigned short* xh  = (unsigned short*)alloc((size_t)N * 64 * 2);
    unsigned short* h   = (unsigned short*)alloc((size_t)N * 64 * 2);
    unsigned short* M   = (unsigned short*)alloc((size_t)N * 512 * 2);  // shared by L1/L2

    hipMemsetAsync(hist, 0, (size_t)KEYS * 4, stream);
    xprep_kernel<<<(N * 8 + 255) / 256, 256, 0, stream>>>(x, xh, N * 8);
    wprep_kernel<<<(9 * 64 * 64 + 255) / 256, 256, 0, stream>>>(W1, root1, wb1, 64);
    wprep_kernel<<<(9 * 64 * 32 + 255) / 256, 256, 0, stream>>>(W2, root2, wb2, 32);
    hist8_kernel<<<(E + 255) / 256, 256, 0, stream>>>(dst, et, hist, rank, E);
    const int nscan = (KEYS + SCAN_TILE - 1) / SCAN_TILE;
    scanA_kernel<<<nscan, 1024, 0, stream>>>(hist, bstart, partial, KEYS);
    scanB_kernel<<<1, 64, 0, stream>>>(partial, pscan, bstart + KEYS, nscan);
    scanC_kernel<<<(KEYS + 1023) / 1024, 1024, 0, stream>>>(bstart, pscan, KEYS);
    scatter_kernel<<<(E + 255) / 256, 256, 0, stream>>>(src, dst, et, rank, bstart, srt, E);

    // layer 1: means of xh, then [xh|M] @ [root1;W1] -> h (relu, f16)
    aggM_kernel<<<(N + 7) / 8, 512, 0, stream>>>(xh, srt, bstart, M, N);
    dense_kernel<64, 1, 1><<<(N + 127) / 128, 512, 0, stream>>>(
        xh, M, wb1, b1, nullptr, h, N);
    // layer 2: means of h, then [h|M] @ [root2;W2] -> out (fp32)
    aggM_kernel<<<(N + 7) / 8, 512, 0, stream>>>(h, srt, bstart, M, N);
    dense_kernel<32, 0, 0><<<(N + 127) / 128, 512, 0, stream>>>(
        h, M, wb2, b2, (float*)d_out, nullptr, N);
}

// Round 4
// 400.831 us; speedup vs baseline: 1.0178x; 1.0178x over previous
//
#include <hip/hip_runtime.h>

typedef _Float16 half8 __attribute__((ext_vector_type(8)));
typedef __attribute__((ext_vector_type(4))) float f32x4;

__device__ __forceinline__ unsigned short f2h(float f) {
    _Float16 h = (_Float16)f;
    return *(unsigned short*)&h;
}
__device__ __forceinline__ float h2f(unsigned short u) {
    _Float16 h = *(_Float16*)&u;
    return (float)h;
}

// ---------- x -> f16 table ----------

__global__ __launch_bounds__(256) void xprep_kernel(
    const float* __restrict__ x, unsigned short* __restrict__ xh, int total8)
{
    int i = blockIdx.x * 256 + threadIdx.x;   // one thread = 8 elements
    if (i >= total8) return;
    const f32x4* p = (const f32x4*)(x + (size_t)i * 8);
    f32x4 u = p[0], v = p[1];
    half8 o;
#pragma unroll
    for (int j = 0; j < 4; ++j) {
        o[j] = (_Float16)u[j];
        o[j + 4] = (_Float16)v[j];
    }
    *(half8*)(xh + (size_t)i * 8) = o;
}

// ---------- preprocessing: counting sort by key = dst*8 + rel ----------

__global__ __launch_bounds__(256) void hist8_kernel(
    const int* __restrict__ dst, const int* __restrict__ et,
    int* __restrict__ hist, int* __restrict__ rank, int E)
{
    int e = blockIdx.x * 256 + threadIdx.x;
    if (e < E) rank[e] = atomicAdd(&hist[dst[e] * 8 + et[e]], 1);
}

#define SCAN_TILE 4096
__global__ __launch_bounds__(1024) void scanA_kernel(
    const int* __restrict__ hist, int* __restrict__ bstart,
    int* __restrict__ partial, int nkeys)
{
    __shared__ int wsum[16];
    const int t = threadIdx.x;
    const int lane = t & 63, w = t >> 6;
    const int base = blockIdx.x * SCAN_TILE + t * 4;
    int v[4];
    int s = 0;
#pragma unroll
    for (int i = 0; i < 4; ++i) {
        v[i] = (base + i < nkeys) ? hist[base + i] : 0;
        s += v[i];
    }
    int inc = s;
#pragma unroll
    for (int off = 1; off < 64; off <<= 1) {
        int u = __shfl_up(inc, off);
        if (lane >= off) inc += u;
    }
    if (lane == 63) wsum[w] = inc;
    __syncthreads();
    if (w == 0 && lane < 16) {
        int ws = wsum[lane];
        int winc = ws;
#pragma unroll
        for (int off = 1; off < 16; off <<= 1) {
            int u = __shfl_up(winc, off);
            if (lane >= off) winc += u;
        }
        wsum[lane] = winc - ws;   // exclusive
    }
    __syncthreads();
    int run = wsum[w] + (inc - s);
    int tbase = run;
#pragma unroll
    for (int i = 0; i < 4; ++i) {
        if (base + i < nkeys) bstart[base + i] = run;
        run += v[i];
    }
    if (t == 1023) partial[blockIdx.x] = tbase + s;   // block total
}

__global__ __launch_bounds__(64) void scanB_kernel(
    const int* __restrict__ partial, int* __restrict__ pscan,
    int* __restrict__ bstart_end, int nblk)
{
    const int lane = threadIdx.x;
    int running = 0;
    for (int b = 0; b < nblk; b += 64) {
        int i = b + lane;
        int o = (i < nblk) ? partial[i] : 0;
        int v = o;
#pragma unroll
        for (int off = 1; off < 64; off <<= 1) {
            int u = __shfl_up(v, off);
            if (lane >= off) v += u;
        }
        if (i < nblk) pscan[i] = running + v - o;
        running += __shfl(v, 63);
    }
    if (lane == 0) *bstart_end = running;   // == E
}

__global__ __launch_bounds__(1024) void scanC_kernel(
    int* __restrict__ bstart, const int* __restrict__ pscan, int nkeys)
{
    int i = blockIdx.x * 1024 + threadIdx.x;
    if (i < nkeys) bstart[i] += pscan[i / SCAN_TILE];
}

// scatter: record = { src , f32 scale = 1/cnt(dst,rel) }
// Per-relation mean folded into a per-edge FMA scale; rel implied by segment.
__global__ __launch_bounds__(256) void scatter_kernel(
    const int* __restrict__ src, const int* __restrict__ dst,
    const int* __restrict__ et, const int* __restrict__ rank,
    const int* __restrict__ bstart, uint2* __restrict__ srt, int E)
{
    int e = blockIdx.x * 256 + threadIdx.x;
    if (e < E) {
        int key = dst[e] * 8 + et[e];
        int b0 = bstart[key];
        int cnt = bstart[key + 1] - b0;           // >= 1 for existing edges
        uint2 rec;
        rec.x = (unsigned)src[e];
        rec.y = __float_as_uint(1.0f / (float)cnt);
        srt[b0 + rank[e]] = rec;
    }
}

// ---------- W preconversion: chunk c in {root, W_0..7}: [c][j][k stride 72] ----------

__global__ __launch_bounds__(256) void wprep_kernel(
    const float* __restrict__ W, const float* __restrict__ root,
    unsigned short* __restrict__ wb, int dout)
{
    int idx = blockIdx.x * 256 + threadIdx.x;
    int total = 9 * 64 * dout;
    if (idx >= total) return;
    int c = idx / (64 * dout);
    int rme = idx % (64 * dout);
    int kk = rme / dout;
    int j = rme % dout;
    float f = (c == 0) ? root[kk * dout + j]
                       : W[(size_t)(c - 1) * 64 * dout + kk * dout + j];
    wb[(size_t)c * dout * 72 + (size_t)j * 72 + kk] = f2h(f);
}

// ---------- fused layer: aggregate means into LDS A-tile, then MFMA dense ----------
// Block = 128 threads (2 waves) = 16 nodes. Wave w aggregates nodes nb16+w*8..+7
// into Atile rows w*8..w*8+7 (row = [x_self | mean_0..mean_7], 576 halfs,
// stride 600 to spread LDS banks). Then both waves do the 16x16x32 f16 MFMA
// dense for their j-columns, W read from global (L1/L2-hot, same lines per block).
// Per-edge inner loop is scalarized: v_readlane gives uniform src+scale ->
// SGPR-base gather, 1 fma/edge; segment boundaries are scalar compares.

template <int DOUT, int RELU, int OUTH>
__global__ __launch_bounds__(128, 4) void fused_kernel(
    const unsigned short* __restrict__ tab,   // (N,64) f16 gather/self table
    const uint2* __restrict__ srt,            // {src, scale} per edge (sorted)
    const int* __restrict__ bstart,           // (N*8 + 1)
    const unsigned short* __restrict__ wb,    // (9, DOUT, 72) f16
    const float* __restrict__ bias,
    float* __restrict__ outf,                 // fp32 out (OUTH=0)
    unsigned short* __restrict__ outh,        // f16 out, stride 64 (OUTH=1)
    int n_nodes)
{
    __shared__ __align__(16) unsigned short Atile[16 * 600];   // 19.2 KB

    const int t = threadIdx.x;
    const int w = t >> 6, lane = t & 63;
    const int quad = lane >> 4, l16 = lane & 15;
    const int nb16 = blockIdx.x * 16;
    const int nb8 = nb16 + w * 8;
    const int KEYS = n_nodes * 8;

    // ---- aggregation phase (wave-private; no cross-wave LDS sharing) ----
    {
        const int nb0 = nb8 * 8;
        int idx = nb0 + lane; if (idx > KEYS) idx = KEYS;
        const int myb = bstart[idx];                       // 64 boundaries, 1 load
        int i64 = nb0 + 64; if (i64 > KEYS) i64 = KEYS;
        const int blast = bstart[i64];                     // 65th boundary
        const int E0 = __builtin_amdgcn_readlane(myb, 0);
        const int E1 = blast;

        // self rows (chunk 0)
#pragma unroll
        for (int i = 0; i < 8; ++i) {
            int node = nb8 + i;
            unsigned short v = 0;
            if (node < n_nodes) v = tab[(size_t)node * 64 + lane];
            Atile[(w * 8 + i) * 600 + lane] = v;
        }

        float acc = 0.f;
        int R = 0;                                         // global segment idx 0..63
        int bnext = __builtin_amdgcn_readlane(myb, 1);

        auto flush_to = [&](int eabs) {
            while (R < 64 && eabs == bnext) {
                Atile[(w * 8 + (R >> 3)) * 600 + 64 + (R & 7) * 64 + lane] = f2h(acc);
                acc = 0.f;
                ++R;
                bnext = (R < 63) ? __builtin_amdgcn_readlane(myb, R + 1) : blast;
            }
        };

        for (int base = E0; base < E1; base += 64) {
            const int blen = min(64, E1 - base);
            uint2 rec; rec.x = 0u; rec.y = 0u;
            if (lane < blen) rec = srt[base + lane];
            int k = 0;
            for (; k + 4 <= blen; k += 4) {
                int q0 = __builtin_amdgcn_readlane((int)rec.x, k);
                int q1 = __builtin_amdgcn_readlane((int)rec.x, k + 1);
                int q2 = __builtin_amdgcn_readlane((int)rec.x, k + 2);
                int q3 = __builtin_amdgcn_readlane((int)rec.x, k + 3);
                float s0 = __uint_as_float((unsigned)__builtin_amdgcn_readlane((int)rec.y, k));
                float s1 = __uint_as_float((unsigned)__builtin_amdgcn_readlane((int)rec.y, k + 1));
                float s2 = __uint_as_float((unsigned)__builtin_amdgcn_readlane((int)rec.y, k + 2));
                float s3 = __uint_as_float((unsigned)__builtin_amdgcn_readlane((int)rec.y, k + 3));
                float v0 = h2f(tab[(size_t)(unsigned)q0 * 64 + lane]);
                float v1 = h2f(tab[(size_t)(unsigned)q1 * 64 + lane]);
                float v2 = h2f(tab[(size_t)(unsigned)q2 * 64 + lane]);
                float v3 = h2f(tab[(size_t)(unsigned)q3 * 64 + lane]);
                flush_to(base + k);     acc = fmaf(v0, s0, acc);
                flush_to(base + k + 1); acc = fmaf(v1, s1, acc);
                flush_to(base + k + 2); acc = fmaf(v2, s2, acc);
                flush_to(base + k + 3); acc = fmaf(v3, s3, acc);
            }
            for (; k < blen; ++k) {
                int q = __builtin_amdgcn_readlane((int)rec.x, k);
                float s = __uint_as_float((unsigned)__builtin_amdgcn_readlane((int)rec.y, k));
                float v = h2f(tab[(size_t)(unsigned)q * 64 + lane]);
                flush_to(base + k);
                acc = fmaf(v, s, acc);
            }
        }
        // drain remaining segments (their ends all == E1)
        while (R < 64) {
            Atile[(w * 8 + (R >> 3)) * 600 + 64 + (R & 7) * 64 + lane] = f2h(acc);
            acc = 0.f;
            ++R;
        }
    }

    __syncthreads();

    // ---- MFMA dense phase ----
    half8 a[18];
    {
        const unsigned short* arow = &Atile[l16 * 600];
#pragma unroll
        for (int c = 0; c < 9; ++c) {
            a[2 * c]     = *(const half8*)(arow + c * 64 + quad * 8);
            a[2 * c + 1] = *(const half8*)(arow + c * 64 + 32 + quad * 8);
        }
    }

    constexpr int JPW = DOUT / 16;      // 4 (DOUT=64) or 2 (DOUT=32)
    constexpr int JPWAVE = JPW / 2;     // per wave: 2 or 1
    f32x4 d[JPWAVE];
#pragma unroll
    for (int i = 0; i < JPWAVE; ++i) d[i] = {0.f, 0.f, 0.f, 0.f};

#pragma unroll
    for (int jw = 0; jw < JPWAVE; ++jw) {
        const int j = (w * JPWAVE + jw) * 16 + l16;
#pragma unroll
        for (int c = 0; c < 9; ++c) {
            half8 b0 = *(const half8*)&wb[c * DOUT * 72 + j * 72 + quad * 8];
            half8 b1 = *(const half8*)&wb[c * DOUT * 72 + j * 72 + 32 + quad * 8];
            d[jw] = __builtin_amdgcn_mfma_f32_16x16x32_f16(a[2 * c], b0, d[jw], 0, 0, 0);
            d[jw] = __builtin_amdgcn_mfma_f32_16x16x32_f16(a[2 * c + 1], b1, d[jw], 0, 0, 0);
        }
    }

    // epilogue: C/D layout col = l16 (j), row = quad*4 + reg (node within tile)
#pragma unroll
    for (int jw = 0; jw < JPWAVE; ++jw) {
        const int j = (w * JPWAVE + jw) * 16 + l16;
        const float bj = bias[j];
#pragma unroll
        for (int r = 0; r < 4; ++r) {
            const int node = nb16 + quad * 4 + r;
            if (node < n_nodes) {
                float v = d[jw][r] + bj;
                if (RELU) v = fmaxf(v, 0.0f);
                if (OUTH) outh[(size_t)node * 64 + j] = f2h(v);
                else      outf[(size_t)node * DOUT + j] = v;
            }
        }
    }
}

extern "C" void kernel_launch(void* const* d_in, const int* in_sizes, int n_in,
                              void* d_out, int out_size, void* d_ws, size_t ws_size,
                              hipStream_t stream) {
    const float* x     = (const float*)d_in[0];
    const float* W1    = (const float*)d_in[1];
    const float* root1 = (const float*)d_in[2];
    const float* b1    = (const float*)d_in[3];
    const float* W2    = (const float*)d_in[4];
    const float* root2 = (const float*)d_in[5];
    const float* b2    = (const float*)d_in[6];
    const int*   src   = (const int*)d_in[7];
    const int*   dst   = (const int*)d_in[8];
    const int*   et    = (const int*)d_in[9];

    const int N = in_sizes[0] / 64;
    const int E = in_sizes[7];
    const int KEYS = N * 8;

    char* p = (char*)d_ws;
    auto alloc = [&](size_t bytes) {
        char* r = p;
        p += (bytes + 15) & ~(size_t)15;
        return r;
    };
    uint2* srt          = (uint2*)alloc((size_t)E * 8);
    int* rank           = (int*)alloc((size_t)E * 4);
    int* hist           = (int*)alloc((size_t)KEYS * 4);
    int* bstart         = (int*)alloc((size_t)(KEYS + 1) * 4);
    int* partial        = (int*)alloc(256 * 4);
    int* pscan          = (int*)alloc(256 * 4);
    unsigned short* wb1 = (unsigned short*)alloc((size_t)9 * 64 * 72 * 2);
    unsigned short* wb2 = (unsigned short*)alloc((size_t)9 * 32 * 72 * 2);
    unsigned short* xh  = (unsigned short*)alloc((size_t)N * 64 * 2);
    unsigned short* h   = (unsigned short*)alloc((size_t)N * 64 * 2);

    hipMemsetAsync(hist, 0, (size_t)KEYS * 4, stream);
    xprep_kernel<<<(N * 8 + 255) / 256, 256, 0, stream>>>(x, xh, N * 8);
    wprep_kernel<<<(9 * 64 * 64 + 255) / 256, 256, 0, stream>>>(W1, root1, wb1, 64);
    wprep_kernel<<<(9 * 64 * 32 + 255) / 256, 256, 0, stream>>>(W2, root2, wb2, 32);
    hist8_kernel<<<(E + 255) / 256, 256, 0, stream>>>(dst, et, hist, rank, E);
    const int nscan = (KEYS + SCAN_TILE - 1) / SCAN_TILE;
    scanA_kernel<<<nscan, 1024, 0, stream>>>(hist, bstart, partial, KEYS);
    scanB_kernel<<<1, 64, 0, stream>>>(partial, pscan, bstart + KEYS, nscan);
    scanC_kernel<<<(KEYS + 1023) / 1024, 1024, 0, stream>>>(bstart, pscan, KEYS);
    scatter_kernel<<<(E + 255) / 256, 256, 0, stream>>>(src, dst, et, rank, bstart, srt, E);

    // layer 1: fused agg+dense over xh -> h (relu, f16)
    fused_kernel<64, 1, 1><<<(N + 15) / 16, 128, 0, stream>>>(
        xh, srt, bstart, wb1, b1, nullptr, h, N);
    // layer 2: fused agg+dense over h -> out (fp32)
    fused_kernel<32, 0, 0><<<(N + 15) / 16, 128, 0, stream>>>(
        h, srt, bstart, wb2, b2, (float*)d_out, nullptr, N);
}

// Round 5
// 315.312 us; speedup vs baseline: 1.2938x; 1.2712x over previous
//
#include <hip/hip_runtime.h>

typedef _Float16 half8 __attribute__((ext_vector_type(8)));
typedef __attribute__((ext_vector_type(4))) float f32x4;

__device__ __forceinline__ unsigned short f2h(float f) {
    _Float16 h = (_Float16)f;
    return *(unsigned short*)&h;
}
__device__ __forceinline__ float h2f(unsigned short u) {
    _Float16 h = *(_Float16*)&u;
    return (float)h;
}

// ---------- merged prep: x->f16, W1/W2 images, hist zero ----------

__device__ __forceinline__ void wprep_body(
    const float* __restrict__ W, const float* __restrict__ root,
    unsigned short* __restrict__ wb, int dout, int idx)
{
    int c = idx / (64 * dout);
    int rme = idx % (64 * dout);
    int kk = rme / dout;
    int j = rme % dout;
    float f = (c == 0) ? root[kk * dout + j]
                       : W[(size_t)(c - 1) * 64 * dout + kk * dout + j];
    wb[(size_t)c * dout * 72 + (size_t)j * 72 + kk] = f2h(f);
}

__global__ __launch_bounds__(256) void prep_kernel(
    const float* __restrict__ x, unsigned short* __restrict__ xh, int n8,
    const float* __restrict__ W1, const float* __restrict__ root1,
    unsigned short* __restrict__ wb1,
    const float* __restrict__ W2, const float* __restrict__ root2,
    unsigned short* __restrict__ wb2,
    int* __restrict__ hist, int nhist4)
{
    int id = blockIdx.x * 256 + threadIdx.x;
    if (id < n8) {                       // x -> f16, 8 elems/thread
        const f32x4* p = (const f32x4*)(x + (size_t)id * 8);
        f32x4 u = p[0], v = p[1];
        half8 o;
#pragma unroll
        for (int j = 0; j < 4; ++j) {
            o[j] = (_Float16)u[j];
            o[j + 4] = (_Float16)v[j];
        }
        *(half8*)(xh + (size_t)id * 8) = o;
        return;
    }
    id -= n8;
    if (id < 9 * 64 * 64) { wprep_body(W1, root1, wb1, 64, id); return; }
    id -= 9 * 64 * 64;
    if (id < 9 * 64 * 32) { wprep_body(W2, root2, wb2, 32, id); return; }
    id -= 9 * 64 * 32;
    if (id < nhist4) ((int4*)hist)[id] = make_int4(0, 0, 0, 0);
}

// ---------- preprocessing: counting sort by key = dst*8 + rel ----------

__global__ __launch_bounds__(256) void hist8_kernel(
    const int* __restrict__ dst, const int* __restrict__ et,
    int* __restrict__ hist, int* __restrict__ rank, int E)
{
    int e = blockIdx.x * 256 + threadIdx.x;
    if (e < E) rank[e] = atomicAdd(&hist[dst[e] * 8 + et[e]], 1);
}

#define SCAN_TILE 4096
__global__ __launch_bounds__(1024) void scanA_kernel(
    const int* __restrict__ hist, int* __restrict__ bstart,
    int* __restrict__ partial, int nkeys)
{
    __shared__ int wsum[16];
    const int t = threadIdx.x;
    const int lane = t & 63, w = t >> 6;
    const int base = blockIdx.x * SCAN_TILE + t * 4;
    int v[4];
    int s = 0;
#pragma unroll
    for (int i = 0; i < 4; ++i) {
        v[i] = (base + i < nkeys) ? hist[base + i] : 0;
        s += v[i];
    }
    int inc = s;
#pragma unroll
    for (int off = 1; off < 64; off <<= 1) {
        int u = __shfl_up(inc, off);
        if (lane >= off) inc += u;
    }
    if (lane == 63) wsum[w] = inc;
    __syncthreads();
    if (w == 0 && lane < 16) {
        int ws = wsum[lane];
        int winc = ws;
#pragma unroll
        for (int off = 1; off < 16; off <<= 1) {
            int u = __shfl_up(winc, off);
            if (lane >= off) winc += u;
        }
        wsum[lane] = winc - ws;   // exclusive
    }
    __syncthreads();
    int run = wsum[w] + (inc - s);
    int tbase = run;
#pragma unroll
    for (int i = 0; i < 4; ++i) {
        if (base + i < nkeys) bstart[base + i] = run;
        run += v[i];
    }
    if (t == 1023) partial[blockIdx.x] = tbase + s;   // block total
}

__global__ __launch_bounds__(64) void scanB_kernel(
    const int* __restrict__ partial, int* __restrict__ pscan,
    int* __restrict__ bstart_end, int nblk)
{
    const int lane = threadIdx.x;
    int running = 0;
    for (int b = 0; b < nblk; b += 64) {
        int i = b + lane;
        int o = (i < nblk) ? partial[i] : 0;
        int v = o;
#pragma unroll
        for (int off = 1; off < 64; off <<= 1) {
            int u = __shfl_up(v, off);
            if (lane >= off) v += u;
        }
        if (i < nblk) pscan[i] = running + v - o;
        running += __shfl(v, 63);
    }
    if (lane == 0) *bstart_end = running;   // == E
}

__global__ __launch_bounds__(1024) void scanC_kernel(
    int* __restrict__ bstart, const int* __restrict__ pscan, int nkeys)
{
    int i = blockIdx.x * 1024 + threadIdx.x;
    if (i < nkeys) bstart[i] += pscan[i / SCAN_TILE];
}

// scatter: record = src only; rel/scale recovered from segment structure.
__global__ __launch_bounds__(256) void scatter_kernel(
    const int* __restrict__ src, const int* __restrict__ dst,
    const int* __restrict__ et, const int* __restrict__ rank,
    const int* __restrict__ bstart, unsigned* __restrict__ srt, int E)
{
    int e = blockIdx.x * 256 + threadIdx.x;
    if (e < E) {
        int key = dst[e] * 8 + et[e];
        srt[bstart[key] + rank[e]] = (unsigned)src[e];
    }
}

// ---------- fused layer: aggregate means into LDS A-tile, then MFMA dense ----------
// Block = 256 threads (4 waves) = 16 nodes; wave w owns 4 nodes (32 segments).
// Agg: lane = feature; per edge: readlane(src) -> SGPR-uniform gather of one
// 128B row, acc += v; segment scale 1/cnt applied at flush (precomputed vector
// rsc, readlane per flush). 8-deep unroll + chunk double-buffer for MLP ~8.
// Dense: 16x16x32 f16 MFMA, wave w = j-tile w (DOUT32: waves 2,3 exit).

template <int DOUT, int RELU, int OUTH>
__global__ __launch_bounds__(256, 6) void fused_kernel(
    const unsigned short* __restrict__ tab,   // (N,64) f16 gather/self table
    const unsigned* __restrict__ srt,         // src per edge (sorted by dst*8+rel)
    const int* __restrict__ bstart,           // (N*8 + 1)
    const unsigned short* __restrict__ wb,    // (9, DOUT, 72) f16
    const float* __restrict__ bias,
    float* __restrict__ outf,                 // fp32 out (OUTH=0)
    unsigned short* __restrict__ outh,        // f16 out, stride 64 (OUTH=1)
    int n_nodes)
{
    __shared__ __align__(16) unsigned short Atile[16 * 600];   // 19.2 KB

    const int t = threadIdx.x;
    const int w = t >> 6, lane = t & 63;
    const int quad = lane >> 4, l16 = lane & 15;
    const int nb16 = blockIdx.x * 16;
    const int nb4 = nb16 + w * 4;
    const int KEYS = n_nodes * 8;

    // ---- aggregation phase (wave-private rows) ----
    {
        const int nb0 = nb4 * 8;                          // 32 keys for this wave
        int idx = nb0 + lane; if (idx > KEYS) idx = KEYS;
        const int myb = bstart[idx];                      // boundaries in lanes 0..32
        const int blast = __builtin_amdgcn_readlane(myb, 32);
        const int E0 = __builtin_amdgcn_readlane(myb, 0);
        const int E1 = blast;

        // per-segment reciprocal counts (lanes 0..31 valid): one vector division
        int cnt = __shfl_down(myb, 1) - myb;
        float rsc = 1.0f / fmaxf((float)cnt, 1.0f);

        // self rows (chunk 0)
#pragma unroll
        for (int i = 0; i < 4; ++i) {
            int node = nb4 + i;
            unsigned short v = 0;
            if (node < n_nodes) v = tab[(size_t)node * 64 + lane];
            Atile[(w * 4 + i) * 600 + lane] = v;
        }

        float acc = 0.f;
        int R = 0;                                        // segment index 0..31
        int bnext = __builtin_amdgcn_readlane(myb, 1);

        auto flushes = [&](int eabs) {
            while (R < 32 && eabs == bnext) {
                float sc = __uint_as_float(
                    __builtin_amdgcn_readlane(__float_as_uint(rsc), R));
                Atile[(w * 4 + (R >> 3)) * 600 + 64 + (R & 7) * 64 + lane] =
                    f2h(acc * sc);
                acc = 0.f;
                ++R;
                bnext = (R < 31) ? __builtin_amdgcn_readlane(myb, R + 1) : blast;
            }
        };

        int base = E0;
        unsigned rec = 0;
        if (base < E1 && lane < E1 - base) rec = srt[base + lane];
        while (base < E1) {
            const int blen = min(64, E1 - base);
            const int nbase = base + 64;
            unsigned recn = 0;
            if (nbase < E1 && lane < E1 - nbase) recn = srt[nbase + lane];

            int k = 0;
            for (; k + 8 <= blen; k += 8) {
                unsigned q0 = (unsigned)__builtin_amdgcn_readlane((int)rec, k);
                unsigned q1 = (unsigned)__builtin_amdgcn_readlane((int)rec, k + 1);
                unsigned q2 = (unsigned)__builtin_amdgcn_readlane((int)rec, k + 2);
                unsigned q3 = (unsigned)__builtin_amdgcn_readlane((int)rec, k + 3);
                unsigned q4 = (unsigned)__builtin_amdgcn_readlane((int)rec, k + 4);
                unsigned q5 = (unsigned)__builtin_amdgcn_readlane((int)rec, k + 5);
                unsigned q6 = (unsigned)__builtin_amdgcn_readlane((int)rec, k + 6);
                unsigned q7 = (unsigned)__builtin_amdgcn_readlane((int)rec, k + 7);
                float v0 = h2f(tab[(size_t)q0 * 64 + lane]);
                float v1 = h2f(tab[(size_t)q1 * 64 + lane]);
                float v2 = h2f(tab[(size_t)q2 * 64 + lane]);
                float v3 = h2f(tab[(size_t)q3 * 64 + lane]);
                float v4 = h2f(tab[(size_t)q4 * 64 + lane]);
                float v5 = h2f(tab[(size_t)q5 * 64 + lane]);
                float v6 = h2f(tab[(size_t)q6 * 64 + lane]);
                float v7 = h2f(tab[(size_t)q7 * 64 + lane]);
                flushes(base + k);     acc += v0;
                flushes(base + k + 1); acc += v1;
                flushes(base + k + 2); acc += v2;
                flushes(base + k + 3); acc += v3;
                flushes(base + k + 4); acc += v4;
                flushes(base + k + 5); acc += v5;
                flushes(base + k + 6); acc += v6;
                flushes(base + k + 7); acc += v7;
            }
            for (; k < blen; ++k) {
                unsigned q = (unsigned)__builtin_amdgcn_readlane((int)rec, k);
                float v = h2f(tab[(size_t)q * 64 + lane]);
                flushes(base + k);
                acc += v;
            }
            base = nbase;
            rec = recn;
        }
        flushes(E1);
        while (R < 32) {   // safety drain (empty trailing segments)
            float sc = __uint_as_float(
                __builtin_amdgcn_readlane(__float_as_uint(rsc), R));
            Atile[(w * 4 + (R >> 3)) * 600 + 64 + (R & 7) * 64 + lane] =
                f2h(acc * sc);
            acc = 0.f;
            ++R;
        }
    }

    __syncthreads();

    // ---- MFMA dense phase: wave w = j-tile w ----
    constexpr int JPW = DOUT / 16;       // 4 (DOUT=64) or 2 (DOUT=32)
    if (JPW == 2 && w >= 2) return;      // DOUT=32: waves 2,3 done (after barrier)

    const int j = w * 16 + l16;
    f32x4 d = {0.f, 0.f, 0.f, 0.f};
    const unsigned short* arow = &Atile[l16 * 600];
#pragma unroll
    for (int c = 0; c < 9; ++c) {
        half8 a0 = *(const half8*)(arow + c * 64 + quad * 8);
        half8 a1 = *(const half8*)(arow + c * 64 + 32 + quad * 8);
        half8 b0 = *(const half8*)&wb[c * DOUT * 72 + j * 72 + quad * 8];
        half8 b1 = *(const half8*)&wb[c * DOUT * 72 + j * 72 + 32 + quad * 8];
        d = __builtin_amdgcn_mfma_f32_16x16x32_f16(a0, b0, d, 0, 0, 0);
        d = __builtin_amdgcn_mfma_f32_16x16x32_f16(a1, b1, d, 0, 0, 0);
    }

    // epilogue: C/D layout col = l16 (j), row = quad*4 + reg (node within tile)
    const float bj = bias[j];
#pragma unroll
    for (int r = 0; r < 4; ++r) {
        const int node = nb16 + quad * 4 + r;
        if (node < n_nodes) {
            float v = d[r] + bj;
            if (RELU) v = fmaxf(v, 0.0f);
            if (OUTH) outh[(size_t)node * 64 + j] = f2h(v);
            else      outf[(size_t)node * DOUT + j] = v;
        }
    }
}

extern "C" void kernel_launch(void* const* d_in, const int* in_sizes, int n_in,
                              void* d_out, int out_size, void* d_ws, size_t ws_size,
                              hipStream_t stream) {
    const float* x     = (const float*)d_in[0];
    const float* W1    = (const float*)d_in[1];
    const float* root1 = (const float*)d_in[2];
    const float* b1    = (const float*)d_in[3];
    const float* W2    = (const float*)d_in[4];
    const float* root2 = (const float*)d_in[5];
    const float* b2    = (const float*)d_in[6];
    const int*   src   = (const int*)d_in[7];
    const int*   dst   = (const int*)d_in[8];
    const int*   et    = (const int*)d_in[9];

    const int N = in_sizes[0] / 64;
    const int E = in_sizes[7];
    const int KEYS = N * 8;

    char* p = (char*)d_ws;
    auto alloc = [&](size_t bytes) {
        char* r = p;
        p += (bytes + 15) & ~(size_t)15;
        return r;
    };
    unsigned* srt       = (unsigned*)alloc((size_t)E * 4);
    int* rank           = (int*)alloc((size_t)E * 4);
    int* hist           = (int*)alloc((size_t)KEYS * 4);
    int* bstart         = (int*)alloc((size_t)(KEYS + 1) * 4);
    int* partial        = (int*)alloc(256 * 4);
    int* pscan          = (int*)alloc(256 * 4);
    unsigned short* wb1 = (unsigned short*)alloc((size_t)9 * 64 * 72 * 2);
    unsigned short* wb2 = (unsigned short*)alloc((size_t)9 * 32 * 72 * 2);
    unsigned short* xh  = (unsigned short*)alloc((size_t)N * 64 * 2);
    unsigned short* h   = (unsigned short*)alloc((size_t)N * 64 * 2);

    const int n8 = N * 8;                 // xprep items
    const int nhist4 = KEYS / 4;          // hist zero items (int4)
    const int prep_items = n8 + 9 * 64 * 64 + 9 * 64 * 32 + nhist4;
    prep_kernel<<<(prep_items + 255) / 256, 256, 0, stream>>>(
        x, xh, n8, W1, root1, wb1, W2, root2, wb2, hist, nhist4);

    hist8_kernel<<<(E + 255) / 256, 256, 0, stream>>>(dst, et, hist, rank, E);
    const int nscan = (KEYS + SCAN_TILE - 1) / SCAN_TILE;
    scanA_kernel<<<nscan, 1024, 0, stream>>>(hist, bstart, partial, KEYS);
    scanB_kernel<<<1, 64, 0, stream>>>(partial, pscan, bstart + KEYS, nscan);
    scanC_kernel<<<(KEYS + 1023) / 1024, 1024, 0, stream>>>(bstart, pscan, KEYS);
    scatter_kernel<<<(E + 255) / 256, 256, 0, stream>>>(src, dst, et, rank, bstart, srt, E);

    // layer 1: fused agg+dense over xh -> h (relu, f16)
    fused_kernel<64, 1, 1><<<(N + 15) / 16, 256, 0, stream>>>(
        xh, srt, bstart, wb1, b1, nullptr, h, N);
    // layer 2: fused agg+dense over h -> out (fp32)
    fused_kernel<32, 0, 0><<<(N + 15) / 16, 256, 0, stream>>>(
        h, srt, bstart, wb2, b2, (float*)d_out, nullptr, N);
}

// Round 6
// 315.164 us; speedup vs baseline: 1.2945x; 1.0005x over previous
//
#include <hip/hip_runtime.h>

typedef _Float16 half8 __attribute__((ext_vector_type(8)));
typedef __attribute__((ext_vector_type(4))) float f32x4;

__device__ __forceinline__ unsigned short f2h(float f) {
    _Float16 h = (_Float16)f;
    return *(unsigned short*)&h;
}
__device__ __forceinline__ float h2f(unsigned short u) {
    _Float16 h = *(_Float16*)&u;
    return (float)h;
}

// ---------- merged prep: x->f16, W1/W2 images, hist zero ----------

__device__ __forceinline__ void wprep_body(
    const float* __restrict__ W, const float* __restrict__ root,
    unsigned short* __restrict__ wb, int dout, int idx)
{
    int c = idx / (64 * dout);
    int rme = idx % (64 * dout);
    int kk = rme / dout;
    int j = rme % dout;
    float f = (c == 0) ? root[kk * dout + j]
                       : W[(size_t)(c - 1) * 64 * dout + kk * dout + j];
    wb[(size_t)c * dout * 72 + (size_t)j * 72 + kk] = f2h(f);
}

__global__ __launch_bounds__(256) void prep_kernel(
    const float* __restrict__ x, unsigned short* __restrict__ xh, int n8,
    const float* __restrict__ W1, const float* __restrict__ root1,
    unsigned short* __restrict__ wb1,
    const float* __restrict__ W2, const float* __restrict__ root2,
    unsigned short* __restrict__ wb2,
    int* __restrict__ hist, int nhist4)
{
    int id = blockIdx.x * 256 + threadIdx.x;
    if (id < n8) {                       // x -> f16, 8 elems/thread
        const f32x4* p = (const f32x4*)(x + (size_t)id * 8);
        f32x4 u = p[0], v = p[1];
        half8 o;
#pragma unroll
        for (int j = 0; j < 4; ++j) {
            o[j] = (_Float16)u[j];
            o[j + 4] = (_Float16)v[j];
        }
        *(half8*)(xh + (size_t)id * 8) = o;
        return;
    }
    id -= n8;
    if (id < 9 * 64 * 64) { wprep_body(W1, root1, wb1, 64, id); return; }
    id -= 9 * 64 * 64;
    if (id < 9 * 64 * 32) { wprep_body(W2, root2, wb2, 32, id); return; }
    id -= 9 * 64 * 32;
    if (id < nhist4) ((int4*)hist)[id] = make_int4(0, 0, 0, 0);
}

// ---------- preprocessing: counting sort by key = dst*8 + rel ----------

__global__ __launch_bounds__(256) void hist8_kernel(
    const int* __restrict__ dst, const int* __restrict__ et,
    int* __restrict__ hist, int* __restrict__ rank, int E)
{
    int e = blockIdx.x * 256 + threadIdx.x;
    if (e < E) rank[e] = atomicAdd(&hist[dst[e] * 8 + et[e]], 1);
}

#define SCAN_TILE 4096
__global__ __launch_bounds__(1024) void scanA_kernel(
    const int* __restrict__ hist, int* __restrict__ bstart,
    int* __restrict__ partial, int nkeys)
{
    __shared__ int wsum[16];
    const int t = threadIdx.x;
    const int lane = t & 63, w = t >> 6;
    const int base = blockIdx.x * SCAN_TILE + t * 4;
    int v[4];
    int s = 0;
#pragma unroll
    for (int i = 0; i < 4; ++i) {
        v[i] = (base + i < nkeys) ? hist[base + i] : 0;
        s += v[i];
    }
    int inc = s;
#pragma unroll
    for (int off = 1; off < 64; off <<= 1) {
        int u = __shfl_up(inc, off);
        if (lane >= off) inc += u;
    }
    if (lane == 63) wsum[w] = inc;
    __syncthreads();
    if (w == 0 && lane < 16) {
        int ws = wsum[lane];
        int winc = ws;
#pragma unroll
        for (int off = 1; off < 16; off <<= 1) {
            int u = __shfl_up(winc, off);
            if (lane >= off) winc += u;
        }
        wsum[lane] = winc - ws;   // exclusive
    }
    __syncthreads();
    int run = wsum[w] + (inc - s);
#pragma unroll
    for (int i = 0; i < 4; ++i) {
        if (base + i < nkeys) bstart[base + i] = run;
        run += v[i];
    }
    if (t == 1023) partial[blockIdx.x] = run;   // block total (run==tbase+s here)
}

__global__ __launch_bounds__(64) void scanB_kernel(
    const int* __restrict__ partial, int* __restrict__ pscan,
    int* __restrict__ bstart_end, int nblk)
{
    const int lane = threadIdx.x;
    int running = 0;
    for (int b = 0; b < nblk; b += 64) {
        int i = b + lane;
        int o = (i < nblk) ? partial[i] : 0;
        int v = o;
#pragma unroll
        for (int off = 1; off < 64; off <<= 1) {
            int u = __shfl_up(v, off);
            if (lane >= off) v += u;
        }
        if (i < nblk) pscan[i] = running + v - o;
        running += __shfl(v, 63);
    }
    if (lane == 0) *bstart_end = running;   // == E
}

// scatter: pos = local bstart + pscan (no scanC pass) + rank.
__global__ __launch_bounds__(256) void scatter_kernel(
    const int* __restrict__ src, const int* __restrict__ dst,
    const int* __restrict__ et, const int* __restrict__ rank,
    const int* __restrict__ bstart, const int* __restrict__ pscan,
    unsigned* __restrict__ srt, int E)
{
    int e = blockIdx.x * 256 + threadIdx.x;
    if (e < E) {
        int key = dst[e] * 8 + et[e];
        srt[bstart[key] + pscan[key >> 12] + rank[e]] = (unsigned)src[e];
    }
}

// ---------- fused layer: aggregate means into LDS A-tile, then MFMA dense ----------
// Block = 256 threads (4 waves) = 16 nodes; wave w owns 4 nodes (32 segments).
// Agg: lane = feature; per edge: readlane(src) -> SGPR-uniform 128B row gather.
// Edges consumed in 16-batches with an explicit 2-stage software pipeline:
// batch b+1's 16 gathers are ISSUED before batch b is consumed, so the branchy
// flush/acc chain runs with 16-32 loads in flight (fixes the MLP=1 serialization
// seen in rocprof: 900 cy/edge/wave). Scale 1/cnt applied once per segment flush.

template <int DOUT, int RELU, int OUTH>
__global__ __launch_bounds__(256, 6) void fused_kernel(
    const unsigned short* __restrict__ tab,   // (N,64) f16 gather/self table
    const unsigned* __restrict__ srt,         // src per edge (sorted by dst*8+rel)
    const int* __restrict__ bstart,           // (N*8+1) LOCAL scan (pre-pscan)
    const int* __restrict__ pscan,            // per-4096-tile offsets
    const unsigned short* __restrict__ wb,    // (9, DOUT, 72) f16
    const float* __restrict__ bias,
    float* __restrict__ outf,                 // fp32 out (OUTH=0)
    unsigned short* __restrict__ outh,        // f16 out, stride 64 (OUTH=1)
    int n_nodes, int Etot)
{
    __shared__ __align__(16) unsigned short Atile[16 * 600];   // 19.2 KB

    const int t = threadIdx.x;
    const int w = t >> 6, lane = t & 63;
    const int quad = lane >> 4, l16 = lane & 15;
    const int nbt = blockIdx.x * 16;
    const int nb4 = nbt + w * 4;
    const int KEYS = n_nodes * 8;

    // ---- aggregation phase (wave-private rows) ----
    {
        const int nb0 = nb4 * 8;                          // 32 keys for this wave
        int idx = nb0 + lane; if (idx > KEYS) idx = KEYS;
        int lv;
        if (idx < KEYS) lv = bstart[idx] + pscan[idx >> 12];
        else            lv = Etot;
        const int E0 = __builtin_amdgcn_readlane(lv, 0);
        const int E1 = __builtin_amdgcn_readlane(lv, 32);

        // per-segment reciprocal counts (lanes 0..31 valid)
        int cntv = __shfl_down(lv, 1) - lv;
        float rsc = 1.0f / fmaxf((float)cntv, 1.0f);

        // self rows (chunk 0)
#pragma unroll
        for (int i = 0; i < 4; ++i) {
            int node = nb4 + i;
            unsigned short v = 0;
            if (node < n_nodes) v = tab[(size_t)node * 64 + lane];
            Atile[(w * 4 + i) * 600 + lane] = v;
        }

        float acc0 = 0.f, acc1 = 0.f;
        int R = 0;                                        // segment index 0..31
        int bnext = __builtin_amdgcn_readlane(lv, 1);

        auto flushes = [&](int eabs) {
            while (R < 32 && eabs == bnext) {
                float sc = __uint_as_float(
                    __builtin_amdgcn_readlane(__float_as_uint(rsc), R));
                Atile[(w * 4 + (R >> 3)) * 600 + 64 + (R & 7) * 64 + lane] =
                    f2h((acc0 + acc1) * sc);
                acc0 = 0.f; acc1 = 0.f;
                ++R;
                bnext = (R < 31) ? __builtin_amdgcn_readlane(lv, R + 1) : E1;
            }
        };

        const char* tabc = (const char*)tab;
        const unsigned loff = (unsigned)(lane << 1);
        unsigned short GA[16], GB[16];

        int base = E0;
        unsigned rec = 0;
        if (base < E1 && lane < E1 - base) rec = srt[base + lane];
        while (base < E1) {
            const int blen = min(64, E1 - base);
            const int nbase = base + 64;
            unsigned recn = 0;
            if (nbase < E1 && lane < E1 - nbase) recn = srt[nbase + lane];

            // issue batch 0 (junk-safe: lanes >= blen hold rec=0 -> row 0)
#pragma unroll
            for (int i = 0; i < 16; ++i) {
                unsigned q = (unsigned)__builtin_amdgcn_readlane((int)rec, i);
                GA[i] = *(const unsigned short*)(tabc + ((size_t)q << 7) + loff);
            }
            for (int b = 0; b < blen; b += 16) {
                if (b + 16 < blen) {          // issue next batch BEFORE consuming
#pragma unroll
                    for (int i = 0; i < 16; ++i) {
                        unsigned q = (unsigned)__builtin_amdgcn_readlane(
                            (int)rec, b + 16 + i);
                        GB[i] = *(const unsigned short*)(
                            tabc + ((size_t)q << 7) + loff);
                    }
                }
                if (b + 16 <= blen) {         // full batch, unguarded consume
#pragma unroll
                    for (int i = 0; i < 16; ++i) {
                        flushes(base + b + i);
                        if (i & 1) acc1 += h2f(GA[i]);
                        else       acc0 += h2f(GA[i]);
                    }
                } else {                      // tail batch, guarded
#pragma unroll
                    for (int i = 0; i < 16; ++i) {
                        if (b + i < blen) {
                            flushes(base + b + i);
                            if (i & 1) acc1 += h2f(GA[i]);
                            else       acc0 += h2f(GA[i]);
                        }
                    }
                }
                if (b + 16 < blen) {
#pragma unroll
                    for (int i = 0; i < 16; ++i) GA[i] = GB[i];
                }
            }
            base = nbase; rec = recn;
        }
        flushes(E1);
        while (R < 32) {   // drain trailing empty segments
            float sc = __uint_as_float(
                __builtin_amdgcn_readlane(__float_as_uint(rsc), R));
            Atile[(w * 4 + (R >> 3)) * 600 + 64 + (R & 7) * 64 + lane] =
                f2h((acc0 + acc1) * sc);
            acc0 = 0.f; acc1 = 0.f;
            ++R;
        }
    }

    __syncthreads();

    // ---- MFMA dense phase: wave w = j-tile w ----
    constexpr int JPW = DOUT / 16;       // 4 (DOUT=64) or 2 (DOUT=32)
    if (JPW == 2 && w >= 2) return;      // DOUT=32: waves 2,3 done (after barrier)

    const int j = w * 16 + l16;
    f32x4 d = {0.f, 0.f, 0.f, 0.f};
    const unsigned short* arow = &Atile[l16 * 600];
#pragma unroll
    for (int c = 0; c < 9; ++c) {
        half8 a0 = *(const half8*)(arow + c * 64 + quad * 8);
        half8 a1 = *(const half8*)(arow + c * 64 + 32 + quad * 8);
        half8 b0 = *(const half8*)&wb[c * DOUT * 72 + j * 72 + quad * 8];
        half8 b1 = *(const half8*)&wb[c * DOUT * 72 + j * 72 + 32 + quad * 8];
        d = __builtin_amdgcn_mfma_f32_16x16x32_f16(a0, b0, d, 0, 0, 0);
        d = __builtin_amdgcn_mfma_f32_16x16x32_f16(a1, b1, d, 0, 0, 0);
    }

    // epilogue: C/D layout col = l16 (j), row = quad*4 + reg (node within tile)
    const float bj = bias[j];
#pragma unroll
    for (int r = 0; r < 4; ++r) {
        const int node = nbt + quad * 4 + r;
        if (node < n_nodes) {
            float v = d[r] + bj;
            if (RELU) v = fmaxf(v, 0.0f);
            if (OUTH) outh[(size_t)node * 64 + j] = f2h(v);
            else      outf[(size_t)node * DOUT + j] = v;
        }
    }
}

extern "C" void kernel_launch(void* const* d_in, const int* in_sizes, int n_in,
                              void* d_out, int out_size, void* d_ws, size_t ws_size,
                              hipStream_t stream) {
    const float* x     = (const float*)d_in[0];
    const float* W1    = (const float*)d_in[1];
    const float* root1 = (const float*)d_in[2];
    const float* b1    = (const float*)d_in[3];
    const float* W2    = (const float*)d_in[4];
    const float* root2 = (const float*)d_in[5];
    const float* b2    = (const float*)d_in[6];
    const int*   src   = (const int*)d_in[7];
    const int*   dst   = (const int*)d_in[8];
    const int*   et    = (const int*)d_in[9];

    const int N = in_sizes[0] / 64;
    const int E = in_sizes[7];
    const int KEYS = N * 8;

    char* p = (char*)d_ws;
    auto alloc = [&](size_t bytes) {
        char* r = p;
        p += (bytes + 15) & ~(size_t)15;
        return r;
    };
    unsigned* srt       = (unsigned*)alloc((size_t)E * 4);
    int* rank           = (int*)alloc((size_t)E * 4);
    int* hist           = (int*)alloc((size_t)KEYS * 4);
    int* bstart         = (int*)alloc((size_t)(KEYS + 1) * 4);
    int* partial        = (int*)alloc(256 * 4);
    int* pscan          = (int*)alloc(256 * 4);
    unsigned short* wb1 = (unsigned short*)alloc((size_t)9 * 64 * 72 * 2);
    unsigned short* wb2 = (unsigned short*)alloc((size_t)9 * 32 * 72 * 2);
    unsigned short* xh  = (unsigned short*)alloc((size_t)N * 64 * 2);
    unsigned short* h   = (unsigned short*)alloc((size_t)N * 64 * 2);

    const int n8 = N * 8;                 // xprep items
    const int nhist4 = KEYS / 4;          // hist zero items (int4)
    const int prep_items = n8 + 9 * 64 * 64 + 9 * 64 * 32 + nhist4;
    prep_kernel<<<(prep_items + 255) / 256, 256, 0, stream>>>(
        x, xh, n8, W1, root1, wb1, W2, root2, wb2, hist, nhist4);

    hist8_kernel<<<(E + 255) / 256, 256, 0, stream>>>(dst, et, hist, rank, E);
    const int nscan = (KEYS + SCAN_TILE - 1) / SCAN_TILE;
    scanA_kernel<<<nscan, 1024, 0, stream>>>(hist, bstart, partial, KEYS);
    scanB_kernel<<<1, 64, 0, stream>>>(partial, pscan, bstart + KEYS, nscan);
    scatter_kernel<<<(E + 255) / 256, 256, 0, stream>>>(
        src, dst, et, rank, bstart, pscan, srt, E);

    // layer 1: fused agg+dense over xh -> h (relu, f16)
    fused_kernel<64, 1, 1><<<(N + 15) / 16, 256, 0, stream>>>(
        xh, srt, bstart, pscan, wb1, b1, nullptr, h, N, E);
    // layer 2: fused agg+dense over h -> out (fp32)
    fused_kernel<32, 0, 0><<<(N + 15) / 16, 256, 0, stream>>>(
        h, srt, bstart, pscan, wb2, b2, (float*)d_out, nullptr, N, E);
}